// Round 4
// baseline (2778.704 us; speedup 1.0000x reference)
//
#include <hip/hip_runtime.h>

#define D_FEAT 128

// out = feat  (EPS == 0, so (1+eps) == 1)
__global__ void init_out_kernel(const float4* __restrict__ feat,
                                float4* __restrict__ out, int n4) {
    int stride = gridDim.x * blockDim.x;
    for (int i = blockIdx.x * blockDim.x + threadIdx.x; i < n4; i += stride)
        out[i] = feat[i];
}

// Edge-parallel scatter: 32 lanes per edge, 4 floats per lane.
__global__ void scatter_edges_kernel(const float* __restrict__ feat,
                                     const int* __restrict__ src,
                                     const int* __restrict__ dst,
                                     float* __restrict__ out, int n_edges) {
    long long stride = (long long)gridDim.x * blockDim.x;
    long long total  = (long long)n_edges * 32;
    for (long long gtid = (long long)blockIdx.x * blockDim.x + threadIdx.x;
         gtid < total; gtid += stride) {
        int edge = (int)(gtid >> 5);   // 32 threads per edge
        int lane = (int)(gtid & 31);
        int s = src[edge];
        int d = dst[edge];
        const float4 v =
            *reinterpret_cast<const float4*>(feat + (size_t)s * D_FEAT + lane * 4);
        float* op = out + (size_t)d * D_FEAT + lane * 4;
        // unsafeAtomicAdd -> global_atomic_add_f32 (HW f32 atomic)
        unsafeAtomicAdd(op + 0, v.x);
        unsafeAtomicAdd(op + 1, v.y);
        unsafeAtomicAdd(op + 2, v.z);
        unsafeAtomicAdd(op + 3, v.w);
    }
}

extern "C" void kernel_launch(void* const* d_in, const int* in_sizes, int n_in,
                              void* d_out, int out_size, void* d_ws, size_t ws_size,
                              hipStream_t stream) {
    const float* feat = (const float*)d_in[0];
    const int*   src  = (const int*)d_in[1];
    const int*   dst  = (const int*)d_in[2];
    float*       out  = (float*)d_out;

    int n_feat  = in_sizes[0];       // N_NODES * D_FEAT
    int n_edges = in_sizes[1];

    int blk = 256;

    // 1) out = feat
    int n4 = n_feat / 4;
    int grid_init = min((n4 + blk - 1) / blk, 2048);
    init_out_kernel<<<grid_init, blk, 0, stream>>>(
        (const float4*)feat, (float4*)out, n4);

    // 2) atomic scatter of feat[src] into out[dst]
    long long total_threads = (long long)n_edges * 32;
    int grid_sc = (int)min((total_threads + blk - 1) / blk, (long long)8192);
    scatter_edges_kernel<<<grid_sc, blk, 0, stream>>>(feat, src, dst, out, n_edges);
}

// Round 7
// 414.535 us; speedup vs baseline: 6.7032x; 6.7032x over previous
//
#include <hip/hip_runtime.h>

#define D_FEAT 128
typedef unsigned int uint32;

// ---------------- CSR build ----------------

__global__ void k_zero(uint32* __restrict__ p, int n) {
    int stride = gridDim.x * blockDim.x;
    for (int i = blockIdx.x * blockDim.x + threadIdx.x; i < n; i += stride)
        p[i] = 0u;
}

__global__ void k_hist(const int* __restrict__ dst, uint32* __restrict__ deg, int e) {
    int i = blockIdx.x * blockDim.x + threadIdx.x;
    if (i < e) atomicAdd(&deg[dst[i]], 1u);
}

// Exclusive scan, 1024 elems/block (256 thr x 4). Writes per-block-local
// exclusive scan to offs and the block total to bsum[blockIdx].
__global__ void k_scan1(const uint32* __restrict__ deg, uint32* __restrict__ offs,
                        uint32* __restrict__ bsum, int n) {
    __shared__ uint32 lds[256];
    int t = threadIdx.x;
    int i0 = blockIdx.x * 1024 + t * 4;
    uint32 v[4];
    for (int k = 0; k < 4; ++k) { int i = i0 + k; v[k] = (i < n) ? deg[i] : 0u; }
    uint32 tsum = v[0] + v[1] + v[2] + v[3];
    lds[t] = tsum; __syncthreads();
    uint32 run = tsum;
    for (int off = 1; off < 256; off <<= 1) {
        uint32 add = (t >= off) ? lds[t - off] : 0u; __syncthreads();
        run += add; lds[t] = run; __syncthreads();
    }
    uint32 p = run - tsum;               // exclusive prefix of this thread's chunk
    for (int k = 0; k < 4; ++k) { int i = i0 + k; if (i < n) offs[i] = p; p += v[k]; }
    if (t == 255) bsum[blockIdx.x] = run; // block total (run of last thread = full sum)
}

// In-place exclusive scan of <=256 block totals, single block.
__global__ void k_scan2(uint32* __restrict__ bsum, int nb) {
    __shared__ uint32 lds[256];
    int t = threadIdx.x;
    uint32 v = (t < nb) ? bsum[t] : 0u;
    lds[t] = v; __syncthreads();
    uint32 run = v;
    for (int off = 1; off < 256; off <<= 1) {
        uint32 add = (t >= off) ? lds[t - off] : 0u; __syncthreads();
        run += add; lds[t] = run; __syncthreads();
    }
    if (t < nb) bsum[t] = run - v;
}

// offs += scanned block total; cursor = offs copy.
__global__ void k_scan3(uint32* __restrict__ offs, uint32* __restrict__ cur,
                        const uint32* __restrict__ bsum, int n) {
    int i0 = blockIdx.x * 1024 + threadIdx.x * 4;
    uint32 add = bsum[blockIdx.x];
    for (int k = 0; k < 4; ++k) {
        int i = i0 + k;
        if (i < n) { uint32 o = offs[i] + add; offs[i] = o; cur[i] = o; }
    }
}

__global__ void k_fill(const int* __restrict__ src, const int* __restrict__ dst,
                       uint32* __restrict__ cur, int* __restrict__ adj, int e) {
    int i = blockIdx.x * blockDim.x + threadIdx.x;
    if (i < e) {
        int d = dst[i];
        uint32 p = atomicAdd(&cur[d], 1u);
        adj[p] = src[i];
    }
}

// ---------------- node-parallel gather-reduce ----------------
// One wave64 per node; lane holds float2 (64*8B = 512B coalesced per row).
// After k_fill, cur[node] == offs[node] + deg[node] == row end.
__global__ void k_gather(const float2* __restrict__ feat2,
                         const uint32* __restrict__ offs,
                         const uint32* __restrict__ endp,
                         const int* __restrict__ adj,
                         float2* __restrict__ out2, int n_nodes) {
    int gtid = blockIdx.x * blockDim.x + threadIdx.x;
    int node = gtid >> 6;
    int lane = gtid & 63;
    if (node >= n_nodes) return;
    float2 acc = feat2[(size_t)node * 64 + lane];   // (1+eps)*feat, eps==0
    int e0 = (int)offs[node];
    int e1 = (int)endp[node];
    for (int b = e0; b < e1; b += 64) {
        int cnt = min(64, e1 - b);
        int a = (lane < cnt) ? adj[b + lane] : 0;
        for (int j = 0; j < cnt; ++j) {
            int s = __shfl(a, j);
            float2 v = feat2[(size_t)s * 64 + lane];
            acc.x += v.x; acc.y += v.y;
        }
    }
    out2[(size_t)node * 64 + lane] = acc;
}

// ---------------- fallback (atomic) path ----------------

__global__ void init_out_kernel(const float4* __restrict__ feat,
                                float4* __restrict__ out, int n4) {
    int stride = gridDim.x * blockDim.x;
    for (int i = blockIdx.x * blockDim.x + threadIdx.x; i < n4; i += stride)
        out[i] = feat[i];
}

__global__ void scatter_edges_kernel(const float* __restrict__ feat,
                                     const int* __restrict__ src,
                                     const int* __restrict__ dst,
                                     float* __restrict__ out, int n_edges) {
    long long stride = (long long)gridDim.x * blockDim.x;
    long long total  = (long long)n_edges * 32;
    for (long long gtid = (long long)blockIdx.x * blockDim.x + threadIdx.x;
         gtid < total; gtid += stride) {
        int edge = (int)(gtid >> 5);
        int lane = (int)(gtid & 31);
        int s = src[edge];
        int d = dst[edge];
        const float4 v =
            *reinterpret_cast<const float4*>(feat + (size_t)s * D_FEAT + lane * 4);
        float* op = out + (size_t)d * D_FEAT + lane * 4;
        unsafeAtomicAdd(op + 0, v.x);
        unsafeAtomicAdd(op + 1, v.y);
        unsafeAtomicAdd(op + 2, v.z);
        unsafeAtomicAdd(op + 3, v.w);
    }
}

extern "C" void kernel_launch(void* const* d_in, const int* in_sizes, int n_in,
                              void* d_out, int out_size, void* d_ws, size_t ws_size,
                              hipStream_t stream) {
    const float* feat = (const float*)d_in[0];
    const int*   src  = (const int*)d_in[1];
    const int*   dst  = (const int*)d_in[2];
    float*       out  = (float*)d_out;

    int n_feat  = in_sizes[0];
    int n_edges = in_sizes[1];
    int n_nodes = n_feat / D_FEAT;
    int nb      = (n_nodes + 1023) / 1024;

    size_t need = ((size_t)3 * n_nodes + 256 + (size_t)n_edges) * sizeof(uint32);

    if (ws_size >= need && nb <= 256) {
        uint32* deg  = (uint32*)d_ws;        // [n_nodes]
        uint32* offs = deg  + n_nodes;       // [n_nodes]
        uint32* cur  = offs + n_nodes;       // [n_nodes]
        uint32* bsum = cur  + n_nodes;       // [256]
        int*    adj  = (int*)(bsum + 256);   // [n_edges]

        int blk = 256;
        k_zero <<<256, blk, 0, stream>>>(deg, n_nodes);
        k_hist <<<(n_edges + blk - 1) / blk, blk, 0, stream>>>(dst, deg, n_edges);
        k_scan1<<<nb, blk, 0, stream>>>(deg, offs, bsum, n_nodes);
        k_scan2<<<1, blk, 0, stream>>>(bsum, nb);
        k_scan3<<<nb, blk, 0, stream>>>(offs, cur, bsum, n_nodes);
        k_fill <<<(n_edges + blk - 1) / blk, blk, 0, stream>>>(src, dst, cur, adj, n_edges);

        long long gthreads = (long long)n_nodes * 64;
        k_gather<<<(int)((gthreads + blk - 1) / blk), blk, 0, stream>>>(
            (const float2*)feat, offs, cur, adj, (float2*)out, n_nodes);
    } else {
        // fallback: atomic scatter
        int blk = 256;
        int n4 = n_feat / 4;
        init_out_kernel<<<min((n4 + blk - 1) / blk, 2048), blk, 0, stream>>>(
            (const float4*)feat, (float4*)out, n4);
        long long total_threads = (long long)n_edges * 32;
        int grid_sc = (int)min((total_threads + blk - 1) / blk, (long long)8192);
        scatter_edges_kernel<<<grid_sc, blk, 0, stream>>>(feat, src, dst, out, n_edges);
    }
}